// Round 5
// baseline (26.766 us; speedup 1.0000x reference)
//
#include <hip/hip_runtime.h>

// CTC greedy decode: B=256, T=1024, C=128, blank = C-1 = 127. Fused single kernel.
//
// One block per batch row, 1024 threads = 16 waves.
//
// Phase 1 (argmax, 8 sweeps of 128 timesteps, TRIPLE-buffered):
//   8 lanes per timestep; lane g=tid&7 loads 4 float4 at byte offsets
//   g*16 + 128*i (i=0..3) => each wave instruction reads 8 full aligned
//   128B lines (1KB). Pipeline is 3 deep: sweep s+2's loads are issued
//   before consuming sweep s, so each wave keeps 8 loads (8KB) in flight
//   and the vmcnt wait for sweep s is decoupled by a full iteration.
//   48 data VGPRs; __launch_bounds__(1024,4) keeps VGPR<=128 (16 waves/CU).
//   Local argmax over 16 elems (first-occurrence, ascending class order),
//   3-step __shfl_xor reduce in the 8-lane group (min-index tie-break),
//   result -> LDS am[t].
//
// Phase 2 (compaction, verified rounds 1-4): collapse repeats, drop
//   blanks, block-wide prefix scan, scatter kept tokens, -1 fill.

constexpr int B = 256;
constexpr int T = 1024;
constexpr int C = 128;
constexpr int BLANK = C - 1;
constexpr int SWEEPS = T / 128;      // 8

__global__ __launch_bounds__(1024, 4)
void ctc_fused_kernel(const float* __restrict__ logits, int* __restrict__ out) {
    const int b    = blockIdx.x;
    const int tid  = threadIdx.x;
    const int lane = tid & 63;
    const int wid  = tid >> 6;          // wave id 0..15

    __shared__ int am[T];
    __shared__ int wsum[16];

    const float* row = logits + (size_t)b * T * C;

    // ---------------- Phase 1: argmax per timestep ----------------
    const int g     = tid & 7;          // lane within 8-lane group
    const int tsub  = tid >> 3;         // timestep within sweep (0..127)
    const int csub  = g * 4;            // class base: csub + 32*i, i=0..3

    float4 buf[3][4];                   // 3-deep pipeline, static indices after unroll
    #pragma unroll
    for (int s0 = 0; s0 < 2; ++s0) {    // prologue: sweeps 0 and 1
        const float* p = row + (size_t)(s0 * 128 + tsub) * C + csub;
        #pragma unroll
        for (int i = 0; i < 4; ++i)
            buf[s0][i] = *reinterpret_cast<const float4*>(p + 32 * i);
    }

    #pragma unroll
    for (int s = 0; s < SWEEPS; ++s) {
        if (s + 2 < SWEEPS) {           // issue sweep s+2 before consuming sweep s
            const float* p = row + (size_t)((s + 2) * 128 + tsub) * C + csub;
            #pragma unroll
            for (int i = 0; i < 4; ++i)
                buf[(s + 2) % 3][i] = *reinterpret_cast<const float4*>(p + 32 * i);
        }

        // consume sweep s: local argmax over 16 elems, first-occurrence.
        const float4* v = buf[s % 3];
        float best = v[0].x; int bidx = csub;
        #pragma unroll
        for (int i = 0; i < 4; ++i) {
            const int cb = csub + 32 * i;
            if (i > 0 && v[i].x > best) { best = v[i].x; bidx = cb; }
            if (v[i].y > best) { best = v[i].y; bidx = cb + 1; }
            if (v[i].z > best) { best = v[i].z; bidx = cb + 2; }
            if (v[i].w > best) { best = v[i].w; bidx = cb + 3; }
        }

        // reduce across the 8 lanes of this timestep (xor 1,2,4 stay in-group).
        #pragma unroll
        for (int off = 1; off <= 4; off <<= 1) {
            float ov = __shfl_xor(best, off, 64);
            int   oi = __shfl_xor(bidx, off, 64);
            if (ov > best || (ov == best && oi < bidx)) { best = ov; bidx = oi; }
        }

        if (g == 0) am[s * 128 + tsub] = bidx;
    }
    __syncthreads();

    // ---------------- Phase 2: compaction ----------------
    const int a    = am[tid];
    const int prev = (tid > 0) ? am[tid - 1] : -1;
    const int keep = (a != prev && a != BLANK) ? 1 : 0;

    // wave-inclusive prefix sum of keep
    int scan = keep;
    #pragma unroll
    for (int off = 1; off <= 32; off <<= 1) {
        int n = __shfl_up(scan, off, 64);
        if (lane >= off) scan += n;
    }
    if (lane == 63) wsum[wid] = scan;
    __syncthreads();

    int waveOff = 0, total = 0;
    #pragma unroll
    for (int w = 0; w < 16; ++w) {
        const int s = wsum[w];
        if (w < wid) waveOff += s;
        total += s;
    }

    int* orow = out + (size_t)b * T;
    if (keep) orow[waveOff + scan - 1] = a;   // positions [0, total)
    if (tid >= total) orow[tid] = -1;         // positions [total, T) — disjoint
}

extern "C" void kernel_launch(void* const* d_in, const int* in_sizes, int n_in,
                              void* d_out, int out_size, void* d_ws, size_t ws_size,
                              hipStream_t stream) {
    const float* logits = (const float*)d_in[0];
    int* out = (int*)d_out;
    ctc_fused_kernel<<<B, 1024, 0, stream>>>(logits, out);
}